// Round 3
// baseline (1617.302 us; speedup 1.0000x reference)
//
#include <hip/hip_runtime.h>
#include <math.h>

// fp32 attention layer via split-bf16 (hi/lo) 3-term MFMA emulation.
// GEMMs use the 256x256 8-phase template (T2 swizzle + T3/T4 counted-vmcnt
// phases + T5 setprio) over K'=3K: segment s of K' selects plane pair
// (Ah,Bh)/(Ah,Bl)/(Al,Bh) at stage time -> standard bf16 GEMM structure.
// Pipeline: split(x,Wqkv) -> GEMM1(qkv planes) -> pack K/V -> split(Wo)
// -> flash attention (LDS-staged, max-free softmax) -> GEMM2(+bias, fp32).

typedef unsigned int u32;
typedef unsigned short u16;
typedef __attribute__((ext_vector_type(8))) short bf16x8;
typedef __attribute__((ext_vector_type(4))) float f32x4;

#define MFMA(a, b, c) __builtin_amdgcn_mfma_f32_16x16x32_bf16((a), (b), (c), 0, 0, 0)

#define GLDS16(g, l) __builtin_amdgcn_global_load_lds( \
    (const __attribute__((address_space(1))) u32*)(g), \
    (__attribute__((address_space(3))) u32*)(l), 16, 0, 0)

__device__ __forceinline__ u16 f2bf(float f) {
  u32 u = __builtin_bit_cast(u32, f);
  return (u16)((u + 0x7fffu + ((u >> 16) & 1u)) >> 16);  // RNE
}
__device__ __forceinline__ float bf2f(u16 h) {
  u32 u = ((u32)h) << 16;
  return __builtin_bit_cast(float, u);
}
__device__ __forceinline__ void split2(float f, u16& h, u16& l) {
  h = f2bf(f);
  l = f2bf(f - bf2f(h));
}
__device__ __forceinline__ bf16x8 ld16(const u16* p) {
  return *reinterpret_cast<const bf16x8*>(p);
}

// ---------------------------------------------------------------- split ----
__global__ void split_kernel(const float* __restrict__ src, u16* __restrict__ hi,
                             u16* __restrict__ lo, long n) {
  long i = ((long)blockIdx.x * 256 + threadIdx.x) * 4;
  if (i >= n) return;
  const float4 v = *reinterpret_cast<const float4*>(src + i);
  ushort4 h, l;
  split2(v.x, h.x, l.x);
  split2(v.y, h.y, l.y);
  split2(v.z, h.z, l.z);
  split2(v.w, h.w, l.w);
  *reinterpret_cast<ushort4*>(hi + i) = h;
  *reinterpret_cast<ushort4*>(lo + i) = l;
}

// --------------------------------------------------- 8-phase 256^2 GEMM ----
// C[M,N] = Ah*Bh^T + Ah*Bl^T + Al*Bh^T, all planes [rows][3072].
// K' = 3*3072 -> NT=144 K-tiles of 64. 8 waves (2M x 4N), wave tile 128x64.
// LDS: 2 dbuf x (A 256x64 + B 256x64) bf16 = 128 KiB, XOR-swizzled
// (chunk ^= row&7; linear glds dest + pre-swizzled per-lane global src).
// Per K-tile: 4 quadrant phases; 1 stage quantum (2 glds/thread) per phase:
//   q0: A1(t+1)->nxt  q1: B1(t+1)->nxt  q2: A0(t+2)->cur  q3: B0(t+2)->cur
// (A0 region dies after q1, B0 after q2 -> writes into cur are race-free;
//  two barriers/phase order cross-wave ds_read vs glds-write.)
// Boundary wait: vmcnt(4) = newest 2 quanta in flight (counted, never 0).
// MODE 0: write C as hi/lo bf16 planes.  MODE 1: fp32 C + bias[col].
template <int MODE>
__global__ __launch_bounds__(512, 2) void gemm8p(
    const u16* __restrict__ Ah, const u16* __restrict__ Al,
    const u16* __restrict__ Bh, const u16* __restrict__ Bl,
    int M, int N,
    u16* __restrict__ Ch, u16* __restrict__ Cl,
    float* __restrict__ Cf, const float* __restrict__ bias) {
  constexpr int TPS = 48;   // K-tiles per segment (3072/64)
  constexpr int NT = 144;   // 3 segments
  __shared__ u16 lds[2][2][256 * 64];
  const int tid = threadIdx.x;
  const int lane = tid & 63;
  const int w = tid >> 6;
  const int wr = w >> 2, wc = w & 3;
  const int lr = lane & 15, lg = lane >> 4;

  const int mt = M >> 8;
  const int nwg = gridDim.x;
  const int bid = blockIdx.x;
  const int wg = (bid & 7) * (nwg >> 3) + (bid >> 3);  // XCD swizzle (nwg%8==0)
  const int bm = wg % mt, bn = wg / mt;

  const int srow8 = lane >> 3;
  const int schunk = lane & 7;

  // stage one 8KB instr of quantum A{mq} / B{nq} for K-tile kt into buf.
  auto stA = [&](int buf, int kt, int mq, int j) {
    const int seg = kt / TPS;
    const int ko = (kt - seg * TPS) * 64;
    const u16* P = (seg < 2) ? Ah : Al;
    const int rb = j * 128 + mq * 64 + w * 8;          // wave-uniform row base
    const int tr = rb + srow8;
    const int gc = (schunk ^ (tr & 7)) * 8;            // inverse-swizzled src col
    GLDS16(P + (long)(bm * 256 + tr) * 3072 + ko + gc, &lds[buf][0][rb * 64]);
  };
  auto stB = [&](int buf, int kt, int nq, int j) {
    const int seg = kt / TPS;
    const int ko = (kt - seg * TPS) * 64;
    const u16* P = (seg == 1) ? Bl : Bh;
    const int rb = j * 128 + (w >> 2) * 64 + nq * 32 + (w & 3) * 8;
    const int tr = rb + srow8;
    const int gc = (schunk ^ (tr & 7)) * 8;
    GLDS16(P + (long)(bn * 256 + tr) * 3072 + ko + gc, &lds[buf][1][rb * 64]);
  };

  f32x4 acc[8][4];
#pragma unroll
  for (int m = 0; m < 8; ++m)
#pragma unroll
    for (int n = 0; n < 4; ++n)
#pragma unroll
      for (int j = 0; j < 4; ++j) acc[m][n][j] = 0.f;

  // prologue: A0(0) B0(0) A1(0) B1(0) A0(1) B0(1); keep newest 2 quanta in flight
  stA(0, 0, 0, 0); stA(0, 0, 0, 1);
  stB(0, 0, 0, 0); stB(0, 0, 0, 1);
  stA(0, 0, 1, 0); stA(0, 0, 1, 1);
  stB(0, 0, 1, 0); stB(0, 0, 1, 1);
  stA(1, 1, 0, 0); stA(1, 1, 0, 1);
  stB(1, 1, 0, 0); stB(1, 1, 0, 1);
  asm volatile("s_waitcnt vmcnt(4)" ::: "memory");
  __builtin_amdgcn_s_barrier();

  const int aRow0 = wr * 128 + lr;
  const int bRow0 = wc * 64 + lr;
  const int c0 = (lg ^ (lr & 7)) * 8;  // swizzled chunk for K-half 0

  for (int t = 0; t < NT; ++t) {
    const int cur = t & 1;
    const u16* LA = lds[cur][0];
    const u16* LB = lds[cur][1];
#pragma unroll
    for (int q = 0; q < 4; ++q) {
      const int mq = q >> 1, nq = q & 1;
      bf16x8 af[4][2], bfr[2][2];
#pragma unroll
      for (int m = 0; m < 4; ++m) {
        const int off = (aRow0 + mq * 64 + m * 16) * 64 + c0;
        af[m][0] = ld16(&LA[off]);
        af[m][1] = ld16(&LA[off ^ 32]);  // K-half 1: chunk bit2 flip
      }
#pragma unroll
      for (int n = 0; n < 2; ++n) {
        const int off = (bRow0 + nq * 32 + n * 16) * 64 + c0;
        bfr[n][0] = ld16(&LB[off]);
        bfr[n][1] = ld16(&LB[off ^ 32]);
      }
      if (q == 0) {
        if (t + 1 < NT) { stA(cur ^ 1, t + 1, 1, 0); stA(cur ^ 1, t + 1, 1, 1); }
      } else if (q == 1) {
        if (t + 1 < NT) { stB(cur ^ 1, t + 1, 1, 0); stB(cur ^ 1, t + 1, 1, 1); }
      } else if (q == 2) {
        if (t + 2 < NT) { stA(cur, t + 2, 0, 0); stA(cur, t + 2, 0, 1); }
      } else {
        if (t + 2 < NT) { stB(cur, t + 2, 0, 0); stB(cur, t + 2, 0, 1); }
      }
      __builtin_amdgcn_s_barrier();
      asm volatile("s_waitcnt lgkmcnt(0)" ::: "memory");
      __builtin_amdgcn_sched_barrier(0);
      __builtin_amdgcn_s_setprio(1);
#pragma unroll
      for (int m = 0; m < 4; ++m)
#pragma unroll
        for (int n = 0; n < 2; ++n) {
          acc[mq * 4 + m][nq * 2 + n] =
              MFMA(af[m][0], bfr[n][0], acc[mq * 4 + m][nq * 2 + n]);
          acc[mq * 4 + m][nq * 2 + n] =
              MFMA(af[m][1], bfr[n][1], acc[mq * 4 + m][nq * 2 + n]);
        }
      __builtin_amdgcn_s_setprio(0);
      if (q == 3) {
        if (t + 2 < NT)
          asm volatile("s_waitcnt vmcnt(4)" ::: "memory");
        else
          asm volatile("s_waitcnt vmcnt(0)" ::: "memory");
      }
      __builtin_amdgcn_s_barrier();
    }
  }

  // epilogue: C/D layout col=lane&15, row=(lane>>4)*4+j (m89-verified)
#pragma unroll
  for (int m = 0; m < 8; ++m)
#pragma unroll
    for (int j = 0; j < 4; ++j) {
      const long row = (long)bm * 256 + wr * 128 + m * 16 + lg * 4 + j;
#pragma unroll
      for (int n = 0; n < 4; ++n) {
        const long col = (long)bn * 256 + wc * 64 + n * 16 + lr;
        const long idx = row * N + col;
        const float v = acc[m][n][j];
        if (MODE == 0) {
          u16 h, l;
          split2(v, h, l);
          Ch[idx] = h;
          Cl[idx] = l;
        } else {
          Cf[idx] = v + bias[col];
        }
      }
    }
}

// ---------------------------------------------------------------- pack K ---
__global__ void pack_k(const u16* __restrict__ QKVh, const u16* __restrict__ QKVl,
                       u16* __restrict__ Kp) {
  const int t = blockIdx.x * 256 + threadIdx.x;
  const int lane = t & 63;
  const int rec3 = t >> 6;
  const int c = rec3 % 3;
  const int kb = (rec3 / 3) & 127;
  const int hl = rec3 / 384;
  const int lr = lane & 15, lg = lane >> 4;
  const long src =
      ((long)((hl >> 5) * 2048 + kb * 16 + lr)) * 9216 + 3072 + (hl & 31) * 96 + c * 32 + lg * 8;
  const long dst = ((long)rec3 * 2) * 512 + lane * 8;
  *reinterpret_cast<bf16x8*>(Kp + dst) = ld16(QKVh + src);
  *reinterpret_cast<bf16x8*>(Kp + dst + 512) = ld16(QKVl + src);
}

// ---------------------------------------------------------------- pack V ---
__global__ __launch_bounds__(256) void pack_v(const u16* __restrict__ QKVh,
                                              const u16* __restrict__ QKVl,
                                              u16* __restrict__ Vp) {
  __shared__ u16 sV[2][32 * 96];
  const int tid = threadIdx.x;
  const int hl = blockIdx.x >> 6;
  const int kq = blockIdx.x & 63;
  const long rowbase = ((long)((hl >> 5) * 2048 + kq * 32)) * 9216 + 6144 + (hl & 31) * 96;
#pragma unroll
  for (int i = 0; i < 3; ++i) {
    const int idx = i * 256 + tid;
    const int pl = idx / 384;
    const int r2 = idx % 384;
    const int row = r2 / 12, cu = r2 % 12;
    const u16* srcp = (pl ? QKVl : QKVh) + rowbase + (long)row * 9216 + cu * 8;
    *reinterpret_cast<bf16x8*>(&sV[pl][row * 96 + cu * 8]) = ld16(srcp);
  }
  __syncthreads();
#pragma unroll
  for (int i = 0; i < 3; ++i) {
    const int idx = i * 256 + tid;
    const int lane = idx & 63;
    const int rl = idx >> 6;
    const int n = rl >> 1, pl = rl & 1;
    const int lr = lane & 15, lg = lane >> 4;
    bf16x8 o;
#pragma unroll
    for (int e = 0; e < 8; ++e) o[e] = (short)sV[pl][(lg * 8 + e) * 96 + n * 16 + lr];
    const long dst = ((((long)hl * 6 + n) * 64 + kq) * 2 + pl) * 512 + lane * 8;
    *reinterpret_cast<bf16x8*>(Vp + dst) = o;
  }
}

// ------------------------------------------------------------- attention ---
__global__ __launch_bounds__(256, 2) void attn_kernel(
    const u16* __restrict__ QKVh, const u16* __restrict__ QKVl,
    const u16* __restrict__ Kp, const u16* __restrict__ Vp,
    u16* __restrict__ AOh, u16* __restrict__ AOl) {
  __shared__ u16 kv[2][24 * 512];
  __shared__ u16 pb[4][2][512];
  const int lane = threadIdx.x & 63;
  const int wv = threadIdx.x >> 6;
  const int lr = lane & 15, lg = lane >> 4;

  const int nwg = gridDim.x;
  const int bid = blockIdx.x;
  const int wg = (bid & 7) * (nwg >> 3) + (bid >> 3);
  const int hl = wg >> 5;
  const int qblk = wg & 31;
  const int b = hl >> 5;
  const int q0 = qblk * 64 + wv * 16;

  bf16x8 qh[3], ql[3];
  {
    const long qofs = ((long)(b * 2048 + q0 + lr)) * 9216 + (hl & 31) * 96 + lg * 8;
#pragma unroll
    for (int c = 0; c < 3; ++c) {
      qh[c] = ld16(QKVh + qofs + c * 32);
      ql[c] = ld16(QKVl + qofs + c * 32);
    }
  }

  f32x4 o_acc[6];
#pragma unroll
  for (int n = 0; n < 6; ++n)
#pragma unroll
    for (int j = 0; j < 4; ++j) o_acc[n][j] = 0.f;
  float lsum[4] = {0.f, 0.f, 0.f, 0.f};

  const float scale = 0.10206207261596577f;  // 96^-0.5
  u16* pbh = pb[wv][0];
  u16* pbl = pb[wv][1];

  auto stage = [&](int nb, int it) {
    const long kbase = ((long)hl * 768 + (long)it * 12) * 512;
    const long vbase = ((long)hl * 768 + (long)it * 2) * 512;
#pragma unroll
    for (int j = 0; j < 6; ++j) {
      const int r = wv * 6 + j;
      const u16* src;
      if (r < 12) {
        const int tt = r / 6, rc = r % 6;
        src = Kp + kbase + ((long)(tt * 6 + rc)) * 512 + lane * 8;
      } else {
        const int r2 = r - 12;
        src = Vp + vbase + ((long)((r2 >> 1) * 128 + (r2 & 1))) * 512 + lane * 8;
      }
      GLDS16(src, &kv[nb][r * 512]);
    }
  };

  stage(0, 0);
  __syncthreads();

  for (int it = 0; it < 64; ++it) {
    const int nb = it & 1;
    if (it < 63) stage(nb ^ 1, it + 1);
    const u16* L = kv[nb];

    f32x4 s0, s1;
#pragma unroll
    for (int j = 0; j < 4; ++j) { s0[j] = 0.f; s1[j] = 0.f; }
#pragma unroll
    for (int c = 0; c < 3; ++c) {
      const bf16x8 kh0 = ld16(L + (c * 2 + 0) * 512 + lane * 8);
      const bf16x8 kl0 = ld16(L + (c * 2 + 1) * 512 + lane * 8);
      const bf16x8 kh1 = ld16(L + (6 + c * 2 + 0) * 512 + lane * 8);
      const bf16x8 kl1 = ld16(L + (6 + c * 2 + 1) * 512 + lane * 8);
      s0 = MFMA(qh[c], kh0, s0);
      s1 = MFMA(qh[c], kh1, s1);
      s0 = MFMA(qh[c], kl0, s0);
      s1 = MFMA(qh[c], kl1, s1);
      s0 = MFMA(ql[c], kh0, s0);
      s1 = MFMA(ql[c], kh1, s1);
    }

#pragma unroll
    for (int j = 0; j < 4; ++j) {
      const float p0 = __expf(fmaf(s0[j], scale, -12.f));
      const float p1 = __expf(fmaf(s1[j], scale, -12.f));
      lsum[j] += p0 + p1;
      const int r = lg * 4 + j;
      const int key = j ^ lg;
      u16 h, l;
      split2(p0, h, l);
      const int a0 = r * 32 + ((((lr >> 3) ^ key) & 3) << 3) + (lr & 7);
      pbh[a0] = h;
      pbl[a0] = l;
      split2(p1, h, l);
      const int a1 = r * 32 + ((((2 + (lr >> 3)) ^ key) & 3) << 3) + (lr & 7);
      pbh[a1] = h;
      pbl[a1] = l;
    }
    const int rkey = (lr & 3) ^ (lr >> 2);
    const int ra = lr * 32 + (((lg ^ rkey) & 3) << 3);
    const bf16x8 pah = ld16(&pbh[ra]);
    const bf16x8 pal = ld16(&pbl[ra]);

#pragma unroll
    for (int n = 0; n < 6; ++n) {
      const bf16x8 vh = ld16(L + (12 + n * 2 + 0) * 512 + lane * 8);
      const bf16x8 vl = ld16(L + (12 + n * 2 + 1) * 512 + lane * 8);
      o_acc[n] = MFMA(pah, vh, o_acc[n]);
      o_acc[n] = MFMA(pah, vl, o_acc[n]);
      o_acc[n] = MFMA(pal, vh, o_acc[n]);
    }
    __syncthreads();
  }

  float inv[4];
#pragma unroll
  for (int j = 0; j < 4; ++j) {
    float rs = lsum[j];
#pragma unroll
    for (int mk = 1; mk < 16; mk <<= 1) rs += __shfl_xor(rs, mk);
    inv[j] = 1.f / rs;
  }
#pragma unroll
  for (int n = 0; n < 6; ++n)
#pragma unroll
    for (int j = 0; j < 4; ++j) {
      const long row = (long)(b * 2048 + q0 + lg * 4 + j);
      const long col = (long)(hl & 31) * 96 + n * 16 + lr;
      u16 h, l;
      split2(o_acc[n][j] * inv[j], h, l);
      AOh[row * 3072 + col] = h;
      AOl[row * 3072 + col] = l;
    }
}

// ---------------------------------------------------------------- launch ---
extern "C" void kernel_launch(void* const* d_in, const int* in_sizes, int n_in,
                              void* d_out, int out_size, void* d_ws, size_t ws_size,
                              hipStream_t stream) {
  const float* x = (const float*)d_in[0];     // [4096][3072]
  const float* wqkv = (const float*)d_in[1];  // [9216][3072]
  const float* wo = (const float*)d_in[2];    // [3072][3072]
  const float* bo = (const float*)d_in[3];    // [3072]
  float* out = (float*)d_out;                 // [4096][3072]
  char* ws = (char*)d_ws;

  const size_t E_X = (size_t)4096 * 3072;
  const size_t E_WQ = (size_t)9216 * 3072;
  const size_t E_QKV = (size_t)4096 * 9216;

  u16* XH = (u16*)ws;
  u16* XL = XH + E_X;
  char* W0 = ws + 4 * E_X;
  u16* WQH = (u16*)W0;
  u16* WQL = WQH + E_WQ;
  char* Q0 = W0 + 4 * E_WQ;
  u16* QKVH = (u16*)Q0;
  u16* QKVL = QKVH + E_QKV;
  char* V0 = Q0 + 4 * E_QKV;
  u16* VP = (u16*)V0;
  u16* KP = (u16*)ws;            // reuses X region after GEMM1
  u16* AOH = (u16*)W0;           // reuses WQKV region after GEMM1
  u16* AOL = AOH + E_X;
  u16* WOH = (u16*)(W0 + 4 * E_X);
  u16* WOL = WOH + (size_t)3072 * 3072;

  const size_t need = 4 * (E_X + E_WQ + E_QKV + E_X);
  if (ws_size < need) return;

  split_kernel<<<12288, 256, 0, stream>>>(x, XH, XL, (long)E_X);
  split_kernel<<<27648, 256, 0, stream>>>(wqkv, WQH, WQL, (long)E_WQ);
  gemm8p<0><<<576, 512, 0, stream>>>(XH, XL, WQH, WQL, 4096, 9216,
                                     QKVH, QKVL, nullptr, nullptr);
  pack_k<<<6144, 256, 0, stream>>>(QKVH, QKVL, KP);
  pack_v<<<4096, 256, 0, stream>>>(QKVH, QKVL, VP);
  split_kernel<<<9216, 256, 0, stream>>>(wo, WOH, WOL, (long)(3072 * 3072));
  attn_kernel<<<2048, 256, 0, stream>>>(QKVH, QKVL, KP, VP, AOH, AOL);
  gemm8p<1><<<192, 512, 0, stream>>>(AOH, AOL, WOH, WOL, 4096, 3072,
                                     nullptr, nullptr, out, bo);
}

// Round 4
// 1375.112 us; speedup vs baseline: 1.1761x; 1.1761x over previous
//
#include <hip/hip_runtime.h>
#include <math.h>

// fp32 attention layer via split-bf16 (hi/lo) 3-term MFMA emulation.
// GEMMs: 256x192 8-phase-style schedule over K'=3K=9216 (segment selects
// plane pair AhBh/AhBl/AlBh at stage time). B-fragments register-resident
// (read once per K-tile) -> 22 ds_read_b128/wave/K-tile (min-ish), T2 XOR
// swizzle, counted staging distance-1, setprio around MFMA clusters.
// Grid: GEMM1 768 = 3 exact CU-rounds; GEMM2 256 = 1 exact round.

typedef unsigned int u32;
typedef unsigned short u16;
typedef __attribute__((ext_vector_type(8))) short bf16x8;
typedef __attribute__((ext_vector_type(4))) float f32x4;

#define MFMA(a, b, c) __builtin_amdgcn_mfma_f32_16x16x32_bf16((a), (b), (c), 0, 0, 0)

#define GLDS16(g, l) __builtin_amdgcn_global_load_lds( \
    (const __attribute__((address_space(1))) u32*)(g), \
    (__attribute__((address_space(3))) u32*)(l), 16, 0, 0)

__device__ __forceinline__ u16 f2bf(float f) {
  u32 u = __builtin_bit_cast(u32, f);
  return (u16)((u + 0x7fffu + ((u >> 16) & 1u)) >> 16);  // RNE
}
__device__ __forceinline__ float bf2f(u16 h) {
  u32 u = ((u32)h) << 16;
  return __builtin_bit_cast(float, u);
}
__device__ __forceinline__ void split2(float f, u16& h, u16& l) {
  h = f2bf(f);
  l = f2bf(f - bf2f(h));
}
__device__ __forceinline__ bf16x8 ld16(const u16* p) {
  return *reinterpret_cast<const bf16x8*>(p);
}

// ---------------------------------------------------------------- split ----
__global__ void split_kernel(const float* __restrict__ src, u16* __restrict__ hi,
                             u16* __restrict__ lo, long n) {
  long i = ((long)blockIdx.x * 256 + threadIdx.x) * 4;
  if (i >= n) return;
  const float4 v = *reinterpret_cast<const float4*>(src + i);
  ushort4 h, l;
  split2(v.x, h.x, l.x);
  split2(v.y, h.y, l.y);
  split2(v.z, h.z, l.z);
  split2(v.w, h.w, l.w);
  *reinterpret_cast<ushort4*>(hi + i) = h;
  *reinterpret_cast<ushort4*>(lo + i) = l;
}

// --------------------------------------------------- 256x192 tiled GEMM ----
// C[M,N] = Ah*Bh^T + Ah*Bl^T + Al*Bh^T, planes [rows][3072]. K' = 9216,
// NT=144 K-tiles of 64. 8 waves (2M x 4N), wave tile 128x48.
// LDS: 2 dbuf x (A 256x64 + B 192x64) bf16 = 112 KiB, XOR-swizzled
// (storage chunk = chunk ^ (row&7); linear glds dest + pre-swizzled src).
// Per K-tile, 4 phases:
//  ph0: rd Bkh0(3)+A0kh0(4), stage A(t+1) j0,j1 | 12 MFMA (A0kh0 x Bkh0)
//  ph1: rd Bkh1(3)+A0kh1(4), stage A(t+1) j2,j3 | 12 MFMA (A0kh1 x Bkh1)
//  ph2: rd A1kh0(4),         stage B(t+1) j0-2  | 12 MFMA (A1kh0 x Bkh0)
//  ph3: rd A1kh1(4)                              | 12 MFMA (A1kh1 x Bkh1)
//  boundary: vmcnt(0) (youngest load >= 1 phase old) + barrier.
// Stage never writes cur -> no intra-tile cross-wave hazard.
// MODE 0: write C as hi/lo bf16 planes.  MODE 1: fp32 C + bias[col].
template <int MODE>
__global__ __launch_bounds__(512, 2) void gemm192(
    const u16* __restrict__ Ah, const u16* __restrict__ Al,
    const u16* __restrict__ Bh, const u16* __restrict__ Bl,
    int M, int N,
    u16* __restrict__ Ch, u16* __restrict__ Cl,
    float* __restrict__ Cf, const float* __restrict__ bias) {
  constexpr int NT = 144;
  constexpr int BOFF = 256 * 64;               // B region offset (u16 elems)
  __shared__ u16 lds[2][(256 + 192) * 64];     // 112 KiB
  const int tid = threadIdx.x;
  const int lane = tid & 63;
  const int w = tid >> 6;
  const int wr = w >> 2, wc = w & 3;
  const int lr = lane & 15, lg = lane >> 4;

  const int mt = M >> 8;  // 16
  const int nwg = gridDim.x;
  const int bid = blockIdx.x;
  const int wg = (bid & 7) * (nwg >> 3) + (bid >> 3);  // XCD swizzle (nwg%8==0)
  const int bm = wg % mt, bn = wg / mt;

  const int srow = lane >> 3;                    // 0..7
  const int sgc = ((lane & 7) ^ srow) * 8;       // inverse-swizzled global col

  // stage 8KB piece j (A: j=0..3 rows j*64..; B: j=0..2) of K-tile kt -> buf
  auto stA = [&](int buf, int kt, int j) {
    const int seg = kt / 48;
    const int ko = (kt - seg * 48) * 64;
    const u16* P = (seg < 2) ? Ah : Al;
    const int r = j * 64 + w * 8 + srow;
    GLDS16(P + (long)(bm * 256 + r) * 3072 + ko + sgc,
           &lds[buf][(j * 64 + w * 8) * 64]);
  };
  auto stB = [&](int buf, int kt, int j) {
    const int seg = kt / 48;
    const int ko = (kt - seg * 48) * 64;
    const u16* P = (seg == 1) ? Bl : Bh;
    const int r = j * 64 + w * 8 + srow;
    GLDS16(P + (long)(bn * 192 + r) * 3072 + ko + sgc,
           &lds[buf][BOFF + (j * 64 + w * 8) * 64]);
  };

  f32x4 acc[8][3];
#pragma unroll
  for (int m = 0; m < 8; ++m)
#pragma unroll
    for (int n = 0; n < 3; ++n)
#pragma unroll
      for (int j = 0; j < 4; ++j) acc[m][n][j] = 0.f;

  // prologue: stage tile 0 fully into buf 0
  stA(0, 0, 0); stA(0, 0, 1); stA(0, 0, 2); stA(0, 0, 3);
  stB(0, 0, 0); stB(0, 0, 1); stB(0, 0, 2);
  asm volatile("s_waitcnt vmcnt(0)" ::: "memory");
  __builtin_amdgcn_s_barrier();

  const int aRow0 = wr * 128 + lr;
  const int bRow0 = wc * 48 + lr;
  const int c0 = (lg ^ (lr & 7)) * 8;  // swizzled chunk addr, K-half 0

#define RD_A(dst, MQ, KH)                                                  \
  _Pragma("unroll") for (int m = 0; m < 4; ++m) dst[m] =                   \
      ld16(&LA[(aRow0 + (MQ)*64 + m * 16) * 64 + (c0 ^ ((KH)*32))]);
#define RD_B(dst, KH)                                                      \
  _Pragma("unroll") for (int n = 0; n < 3; ++n) dst[n] =                   \
      ld16(&LB[(bRow0 + n * 16) * 64 + (c0 ^ ((KH)*32))]);
#define DO_MFMA(a, b, MQ)                                                  \
  __builtin_amdgcn_s_setprio(1);                                           \
  _Pragma("unroll") for (int m = 0; m < 4; ++m)                            \
  _Pragma("unroll") for (int n = 0; n < 3; ++n)                            \
      acc[(MQ)*4 + m][n] = MFMA(a[m], b[n], acc[(MQ)*4 + m][n]);           \
  __builtin_amdgcn_s_setprio(0);
#define PH_SYNC()                                                          \
  __builtin_amdgcn_s_barrier();                                            \
  asm volatile("s_waitcnt lgkmcnt(0)" ::: "memory");                       \
  __builtin_amdgcn_sched_barrier(0);

  for (int t = 0; t < NT; ++t) {
    const int cur = t & 1;
    const int nxt = cur ^ 1;
    const bool hn = (t + 1 < NT);
    const u16* LA = &lds[cur][0];
    const u16* LB = &lds[cur][BOFF];
    bf16x8 a0[4], a1[4], bk0[3], bk1[3];
    // ph0
    RD_B(bk0, 0);
    RD_A(a0, 0, 0);
    if (hn) { stA(nxt, t + 1, 0); stA(nxt, t + 1, 1); }
    PH_SYNC();
    DO_MFMA(a0, bk0, 0);
    __builtin_amdgcn_s_barrier();
    // ph1
    RD_B(bk1, 1);
    RD_A(a0, 0, 1);
    if (hn) { stA(nxt, t + 1, 2); stA(nxt, t + 1, 3); }
    PH_SYNC();
    DO_MFMA(a0, bk1, 0);
    __builtin_amdgcn_s_barrier();
    // ph2
    RD_A(a1, 1, 0);
    if (hn) { stB(nxt, t + 1, 0); stB(nxt, t + 1, 1); stB(nxt, t + 1, 2); }
    PH_SYNC();
    DO_MFMA(a1, bk0, 1);
    __builtin_amdgcn_s_barrier();
    // ph3
    RD_A(a1, 1, 1);
    PH_SYNC();
    DO_MFMA(a1, bk1, 1);
    asm volatile("s_waitcnt vmcnt(0)" ::: "memory");  // t+1 staged (loads old)
    __builtin_amdgcn_s_barrier();
  }
#undef RD_A
#undef RD_B
#undef DO_MFMA
#undef PH_SYNC

  // epilogue: C/D layout col=lane&15, row=(lane>>4)*4+j (m89-verified)
#pragma unroll
  for (int m = 0; m < 8; ++m)
#pragma unroll
    for (int j = 0; j < 4; ++j) {
      const long row = (long)bm * 256 + wr * 128 + m * 16 + lg * 4 + j;
#pragma unroll
      for (int n = 0; n < 3; ++n) {
        const long col = (long)bn * 192 + wc * 48 + n * 16 + lr;
        const long idx = row * N + col;
        const float v = acc[m][n][j];
        if (MODE == 0) {
          u16 h, l;
          split2(v, h, l);
          Ch[idx] = h;
          Cl[idx] = l;
        } else {
          Cf[idx] = v + bias[col];
        }
      }
    }
}

// ---------------------------------------------------------------- pack K ---
__global__ void pack_k(const u16* __restrict__ QKVh, const u16* __restrict__ QKVl,
                       u16* __restrict__ Kp) {
  const int t = blockIdx.x * 256 + threadIdx.x;
  const int lane = t & 63;
  const int rec3 = t >> 6;
  const int c = rec3 % 3;
  const int kb = (rec3 / 3) & 127;
  const int hl = rec3 / 384;
  const int lr = lane & 15, lg = lane >> 4;
  const long src =
      ((long)((hl >> 5) * 2048 + kb * 16 + lr)) * 9216 + 3072 + (hl & 31) * 96 + c * 32 + lg * 8;
  const long dst = ((long)rec3 * 2) * 512 + lane * 8;
  *reinterpret_cast<bf16x8*>(Kp + dst) = ld16(QKVh + src);
  *reinterpret_cast<bf16x8*>(Kp + dst + 512) = ld16(QKVl + src);
}

// ---------------------------------------------------------------- pack V ---
__global__ __launch_bounds__(256) void pack_v(const u16* __restrict__ QKVh,
                                              const u16* __restrict__ QKVl,
                                              u16* __restrict__ Vp) {
  __shared__ u16 sV[2][32 * 96];
  const int tid = threadIdx.x;
  const int hl = blockIdx.x >> 6;
  const int kq = blockIdx.x & 63;
  const long rowbase = ((long)((hl >> 5) * 2048 + kq * 32)) * 9216 + 6144 + (hl & 31) * 96;
#pragma unroll
  for (int i = 0; i < 3; ++i) {
    const int idx = i * 256 + tid;
    const int pl = idx / 384;
    const int r2 = idx % 384;
    const int row = r2 / 12, cu = r2 % 12;
    const u16* srcp = (pl ? QKVl : QKVh) + rowbase + (long)row * 9216 + cu * 8;
    *reinterpret_cast<bf16x8*>(&sV[pl][row * 96 + cu * 8]) = ld16(srcp);
  }
  __syncthreads();
#pragma unroll
  for (int i = 0; i < 3; ++i) {
    const int idx = i * 256 + tid;
    const int lane = idx & 63;
    const int rl = idx >> 6;
    const int n = rl >> 1, pl = rl & 1;
    const int lr = lane & 15, lg = lane >> 4;
    bf16x8 o;
#pragma unroll
    for (int e = 0; e < 8; ++e) o[e] = (short)sV[pl][(lg * 8 + e) * 96 + n * 16 + lr];
    const long dst = ((((long)hl * 6 + n) * 64 + kq) * 2 + pl) * 512 + lane * 8;
    *reinterpret_cast<bf16x8*>(Vp + dst) = o;
  }
}

// ------------------------------------------------------------- attention ---
__global__ __launch_bounds__(256, 2) void attn_kernel(
    const u16* __restrict__ QKVh, const u16* __restrict__ QKVl,
    const u16* __restrict__ Kp, const u16* __restrict__ Vp,
    u16* __restrict__ AOh, u16* __restrict__ AOl) {
  __shared__ u16 kv[2][24 * 512];
  __shared__ u16 pb[4][2][512];
  const int lane = threadIdx.x & 63;
  const int wv = threadIdx.x >> 6;
  const int lr = lane & 15, lg = lane >> 4;

  const int nwg = gridDim.x;
  const int bid = blockIdx.x;
  const int wg = (bid & 7) * (nwg >> 3) + (bid >> 3);
  const int hl = wg >> 5;
  const int qblk = wg & 31;
  const int b = hl >> 5;
  const int q0 = qblk * 64 + wv * 16;

  bf16x8 qh[3], ql[3];
  {
    const long qofs = ((long)(b * 2048 + q0 + lr)) * 9216 + (hl & 31) * 96 + lg * 8;
#pragma unroll
    for (int c = 0; c < 3; ++c) {
      qh[c] = ld16(QKVh + qofs + c * 32);
      ql[c] = ld16(QKVl + qofs + c * 32);
    }
  }

  f32x4 o_acc[6];
#pragma unroll
  for (int n = 0; n < 6; ++n)
#pragma unroll
    for (int j = 0; j < 4; ++j) o_acc[n][j] = 0.f;
  float lsum[4] = {0.f, 0.f, 0.f, 0.f};

  const float scale = 0.10206207261596577f;  // 96^-0.5
  u16* pbh = pb[wv][0];
  u16* pbl = pb[wv][1];

  auto stage = [&](int nb, int it) {
    const long kbase = ((long)hl * 768 + (long)it * 12) * 512;
    const long vbase = ((long)hl * 768 + (long)it * 2) * 512;
#pragma unroll
    for (int j = 0; j < 6; ++j) {
      const int r = wv * 6 + j;
      const u16* src;
      if (r < 12) {
        const int tt = r / 6, rc = r % 6;
        src = Kp + kbase + ((long)(tt * 6 + rc)) * 512 + lane * 8;
      } else {
        const int r2 = r - 12;
        src = Vp + vbase + ((long)((r2 >> 1) * 128 + (r2 & 1))) * 512 + lane * 8;
      }
      GLDS16(src, &kv[nb][r * 512]);
    }
  };

  stage(0, 0);
  __syncthreads();

  for (int it = 0; it < 64; ++it) {
    const int nb = it & 1;
    if (it < 63) stage(nb ^ 1, it + 1);
    const u16* L = kv[nb];

    f32x4 s0, s1;
#pragma unroll
    for (int j = 0; j < 4; ++j) { s0[j] = 0.f; s1[j] = 0.f; }
#pragma unroll
    for (int c = 0; c < 3; ++c) {
      const bf16x8 kh0 = ld16(L + (c * 2 + 0) * 512 + lane * 8);
      const bf16x8 kl0 = ld16(L + (c * 2 + 1) * 512 + lane * 8);
      const bf16x8 kh1 = ld16(L + (6 + c * 2 + 0) * 512 + lane * 8);
      const bf16x8 kl1 = ld16(L + (6 + c * 2 + 1) * 512 + lane * 8);
      s0 = MFMA(qh[c], kh0, s0);
      s1 = MFMA(qh[c], kh1, s1);
      s0 = MFMA(qh[c], kl0, s0);
      s1 = MFMA(qh[c], kl1, s1);
      s0 = MFMA(ql[c], kh0, s0);
      s1 = MFMA(ql[c], kh1, s1);
    }

#pragma unroll
    for (int j = 0; j < 4; ++j) {
      const float p0 = __expf(fmaf(s0[j], scale, -12.f));
      const float p1 = __expf(fmaf(s1[j], scale, -12.f));
      lsum[j] += p0 + p1;
      const int r = lg * 4 + j;
      const int key = j ^ lg;
      u16 h, l;
      split2(p0, h, l);
      const int a0 = r * 32 + ((((lr >> 3) ^ key) & 3) << 3) + (lr & 7);
      pbh[a0] = h;
      pbl[a0] = l;
      split2(p1, h, l);
      const int a1 = r * 32 + ((((2 + (lr >> 3)) ^ key) & 3) << 3) + (lr & 7);
      pbh[a1] = h;
      pbl[a1] = l;
    }
    const int rkey = (lr & 3) ^ (lr >> 2);
    const int ra = lr * 32 + (((lg ^ rkey) & 3) << 3);
    const bf16x8 pah = ld16(&pbh[ra]);
    const bf16x8 pal = ld16(&pbl[ra]);

#pragma unroll
    for (int n = 0; n < 6; ++n) {
      const bf16x8 vh = ld16(L + (12 + n * 2 + 0) * 512 + lane * 8);
      const bf16x8 vl = ld16(L + (12 + n * 2 + 1) * 512 + lane * 8);
      o_acc[n] = MFMA(pah, vh, o_acc[n]);
      o_acc[n] = MFMA(pah, vl, o_acc[n]);
      o_acc[n] = MFMA(pal, vh, o_acc[n]);
    }
    __syncthreads();
  }

  float inv[4];
#pragma unroll
  for (int j = 0; j < 4; ++j) {
    float rs = lsum[j];
#pragma unroll
    for (int mk = 1; mk < 16; mk <<= 1) rs += __shfl_xor(rs, mk);
    inv[j] = 1.f / rs;
  }
#pragma unroll
  for (int n = 0; n < 6; ++n)
#pragma unroll
    for (int j = 0; j < 4; ++j) {
      const long row = (long)(b * 2048 + q0 + lg * 4 + j);
      const long col = (long)(hl & 31) * 96 + n * 16 + lr;
      u16 h, l;
      split2(o_acc[n][j] * inv[j], h, l);
      AOh[row * 3072 + col] = h;
      AOl[row * 3072 + col] = l;
    }
}

// ---------------------------------------------------------------- launch ---
extern "C" void kernel_launch(void* const* d_in, const int* in_sizes, int n_in,
                              void* d_out, int out_size, void* d_ws, size_t ws_size,
                              hipStream_t stream) {
  const float* x = (const float*)d_in[0];     // [4096][3072]
  const float* wqkv = (const float*)d_in[1];  // [9216][3072]
  const float* wo = (const float*)d_in[2];    // [3072][3072]
  const float* bo = (const float*)d_in[3];    // [3072]
  float* out = (float*)d_out;                 // [4096][3072]
  char* ws = (char*)d_ws;

  const size_t E_X = (size_t)4096 * 3072;
  const size_t E_WQ = (size_t)9216 * 3072;
  const size_t E_QKV = (size_t)4096 * 9216;

  u16* XH = (u16*)ws;
  u16* XL = XH + E_X;
  char* W0 = ws + 4 * E_X;
  u16* WQH = (u16*)W0;
  u16* WQL = WQH + E_WQ;
  char* Q0 = W0 + 4 * E_WQ;
  u16* QKVH = (u16*)Q0;
  u16* QKVL = QKVH + E_QKV;
  char* V0 = Q0 + 4 * E_QKV;
  u16* VP = (u16*)V0;
  u16* KP = (u16*)ws;            // reuses X region after GEMM1
  u16* AOH = (u16*)W0;           // reuses WQKV region after GEMM1
  u16* AOL = AOH + E_X;
  u16* WOH = (u16*)(W0 + 4 * E_X);
  u16* WOL = WOH + (size_t)3072 * 3072;

  const size_t need = 4 * (E_X + E_WQ + E_QKV + E_X);
  if (ws_size < need) return;

  split_kernel<<<12288, 256, 0, stream>>>(x, XH, XL, (long)E_X);
  split_kernel<<<27648, 256, 0, stream>>>(wqkv, WQH, WQL, (long)E_WQ);
  gemm192<0><<<768, 512, 0, stream>>>(XH, XL, WQH, WQL, 4096, 9216,
                                      QKVH, QKVL, nullptr, nullptr);
  pack_k<<<6144, 256, 0, stream>>>(QKVH, QKVL, KP);
  pack_v<<<4096, 256, 0, stream>>>(QKVH, QKVL, VP);
  split_kernel<<<9216, 256, 0, stream>>>(wo, WOH, WOL, (long)(3072 * 3072));
  attn_kernel<<<2048, 256, 0, stream>>>(QKVH, QKVL, KP, VP, AOH, AOL);
  gemm192<1><<<256, 512, 0, stream>>>(AOH, AOL, WOH, WOL, 4096, 3072,
                                      nullptr, nullptr, out, bo);
}